// Round 10
// baseline (329.553 us; speedup 1.0000x reference)
//
#include <hip/hip_runtime.h>
#include <math.h>

#define S_ 4
#define R_ 2048
#define K_ 128
#define C_ 32
#define RES_ 128
#define G_ 128
#define H_ 128

typedef __bf16 bf16x8 __attribute__((ext_vector_type(8)));
typedef float f32x4 __attribute__((ext_vector_type(4)));
typedef float f32x2 __attribute__((ext_vector_type(2)));
typedef unsigned short u16x8 __attribute__((ext_vector_type(8)));

// ws layout (in floats)
#define CODET_OFF 0
#define CODET_SZ  (S_*3*RES_*RES_*C_/2)   // bf16: 3145728 floats
#define W1F_OFF   (CODET_OFF + CODET_SZ)
#define W1F_SZ    (128*96/2)              // 6144 floats
#define W2F_OFF   (W1F_OFF + W1F_SZ)
#define W2F_SZ    (128*128/2)             // 8192 floats
#define GB_OFF    (W2F_OFF + W2F_SZ)
#define GB_SZ     (S_*G_*G_*G_/32)        // 262144 uint words
#define SR_OFF    (GB_OFF + GB_SZ)        // 4194304 floats

// Unified LDS row stride (bf16 elements). 272 B row stride: 16B-multiple
// (aligned b128), consecutive rows offset by 4 banks -> worst 2-way = free.
#define ROWP 136

__device__ __forceinline__ unsigned short f2bf(float x) {
  unsigned int u = __float_as_uint(x);
  unsigned int r = u + 0x7fffu + ((u >> 16) & 1u);
  return (unsigned short)(r >> 16);
}

// ---------------------------------------------------------------------------
// K0 (merged pre-pass):
//   blocks 0..3071   : transpose+cvt code (S,3,C,RES,RES) f32 -> (S,3,RES,RES,C) bf16
//   blocks 3072..4095: density bitmask
//   blocks 4096..4111: weight fragments in MFMA B-operand lane order (16-way split)
// ---------------------------------------------------------------------------
__global__ __launch_bounds__(256) void k_pre(
    const float* __restrict__ src, unsigned short* __restrict__ dst,
    const int* __restrict__ dgrid, unsigned int* __restrict__ gbits,
    const float* __restrict__ W1, const float* __restrict__ W2,
    unsigned short* __restrict__ W1F, unsigned short* __restrict__ W2F) {
  __shared__ float tile[32 * 65];
  const int t = threadIdx.x;
  const int b = blockIdx.x;
  if (b < 3072) {
    const int slab = b >> 8;
    const int xy0 = (b & 255) << 6;
    const float* sp = src + slab * (C_ * RES_ * RES_);
    unsigned short* dp = dst + slab * (RES_ * RES_ * C_);
    const int i = t & 63, cg = t >> 6;
#pragma unroll
    for (int j = 0; j < 8; ++j) {
      int c = cg * 8 + j;
      tile[c * 65 + i] = sp[c * (RES_ * RES_) + xy0 + i];
    }
    __syncthreads();
    const int i2 = t >> 2, sub = t & 3;
    u16x8 pk;
#pragma unroll
    for (int j = 0; j < 8; ++j) pk[j] = f2bf(tile[(sub * 8 + j) * 65 + i2]);
    *(u16x8*)(dp + (xy0 + i2) * C_ + sub * 8) = pk;
  } else if (b < 4096) {
    const int wi = (b - 3072) * 256 + t;
    const int base = wi * 32;
    unsigned int m = 0;
#pragma unroll 8
    for (int j = 0; j < 32; ++j) m |= (dgrid[base + j] > 0 ? (1u << j) : 0u);
    gbits[wi] = m;
  } else {
    const int slice = b - 4096;  // 0..15
    for (int i = slice * 256 + t; i < 128 * 96; i += 16 * 256) {
      const int j = i & 7, lane = (i >> 3) & 63, fi = i >> 9;
      const int nt = fi / 3, kt = fi - 3 * nt;
      const int k = kt * 32 + (lane >> 4) * 8 + j;
      const int n = nt * 16 + (lane & 15);
      W1F[i] = f2bf(W1[k * H_ + n]);
    }
    for (int i = slice * 256 + t; i < 128 * 128; i += 16 * 256) {
      const int j = i & 7, lane = (i >> 3) & 63, fi = i >> 9;
      const int nt = fi >> 2, kt = fi & 3;
      const int k = kt * 32 + (lane >> 4) * 8 + j;
      const int n = nt * 16 + (lane & 15);
      W2F[i] = f2bf(W2[k * H_ + n]);
    }
  }
}

// ---------------------------------------------------------------------------
__device__ __forceinline__ void near_far(float ox, float oy, float oz,
                                         float dx, float dy, float dz,
                                         float& nearv, float& farv) {
  float ddx = fabsf(dx) < 1e-9f ? 1e-9f : dx;
  float ddy = fabsf(dy) < 1e-9f ? 1e-9f : dy;
  float ddz = fabsf(dz) < 1e-9f ? 1e-9f : dz;
  float ix = 1.f / ddx, iy = 1.f / ddy, iz = 1.f / ddz;
  float t1x = (-1.f - ox) * ix, t2x = (1.f - ox) * ix;
  float t1y = (-1.f - oy) * iy, t2y = (1.f - oy) * iy;
  float t1z = (-1.f - oz) * iz, t2z = (1.f - oz) * iz;
  float mnx = fminf(t1x, t2x), mxx = fmaxf(t1x, t2x);
  float mny = fminf(t1y, t2y), mxy = fmaxf(t1y, t2y);
  float mnz = fminf(t1z, t2z), mxz = fmaxf(t1z, t2z);
  nearv = fmaxf(fmaxf(fmaxf(mnx, mny), mnz), 0.2f);
  farv = fmaxf(fminf(fminf(mxx, mxy), mxz), nearv);
}

// ---------------------------------------------------------------------------
// K1: fused sampling + MLP (r9 skeleton: 4 waves, wave-local LDS, aliased
// feats/h1 buffer, no barriers). Round-10 deltas:
//  - bf16 packing via v_perm truncation (RTZ) in gather (1 op vs ~10)
//  - h1 store as high-half truncation (ds_write_b16_d16_hi, no f2bf chain)
//  - occupancy-grid word loaded at kernel ENTRY (latency hidden), used at end
//  - launch_bounds (256,8)
// ---------------------------------------------------------------------------
__global__ __launch_bounds__(256, 8) void k_fused(
    const float* __restrict__ rays_o, const float* __restrict__ rays_d,
    const unsigned short* __restrict__ codeT, const unsigned int* __restrict__ gbits,
    const unsigned short* __restrict__ W1F, const float* __restrict__ b1,
    const unsigned short* __restrict__ W2F, const float* __restrict__ b2,
    const float* __restrict__ W3, const float* __restrict__ b3,
    float* __restrict__ sr) {
  __shared__ __align__(16) unsigned short smem[64 * ROWP];  // 17408 B (fA & h1 alias)
  unsigned short* fA = smem;   // feats: rows [p][0..96)
  unsigned short* h1s = smem;  // h1:    rows [m][0..128)

  const int t = threadIdx.x;
  const int w = t >> 6, lane = t & 63;
  const int quad = lane >> 4, ln = lane & 15;
  const int p = t >> 2, q = t & 3;  // sampling role: point p, channel-quarter q
  const int pG0 = blockIdx.x * 64;
  const int s = blockIdx.x >> 12;
  const int r = (blockIdx.x >> 1) & (R_ - 1);
  const int kbase = (blockIdx.x & 1) * 64;

  const float* ob = rays_o + (s * R_ + r) * 3;
  const float* db = rays_d + (s * R_ + r) * 3;
  const float ox = ob[0], oy = ob[1], oz = ob[2];
  const float dx = db[0], dy = db[1], dz = db[2];
  float nearv, farv;
  near_far(ox, oy, oz, dx, dy, dz, nearv, farv);

  // ---- EARLY occupancy-grid load for this lane's epilogue point m_o ----
  const int q_s = ln & 3, rr_s = ln >> 2;
  const int m_o = 16 * w + quad * 4 + rr_s;
  unsigned int occword;
  int occbit;
  {
    const float zm = nearv + (farv - nearv) * ((kbase + m_o + 0.5f) * (1.0f / K_));
    const float pxm = fminf(fmaxf(ox + dx * zm, -1.f), 1.f);
    const float pym = fminf(fmaxf(oy + dy * zm, -1.f), 1.f);
    const float pzm = fminf(fmaxf(oz + dz * zm, -1.f), 1.f);
    const int i0 = min((int)((pxm + 1.f) * 64.f), G_ - 1);
    const int i1 = min((int)((pym + 1.f) * 64.f), G_ - 1);
    const int i2 = min((int)((pzm + 1.f) * 64.f), G_ - 1);
    const int bidx = ((s * G_ + i0) * G_ + i1) * G_ + i2;
    occword = gbits[bidx >> 5];  // issued early; consumed at the very end
    occbit = bidx & 31;
  }

  // ---- this thread's sample point ----
  const float zs = nearv + (farv - nearv) * ((kbase + p + 0.5f) * (1.0f / K_));
  const float px = fminf(fmaxf(ox + dx * zs, -1.f), 1.f);
  const float py = fminf(fmaxf(oy + dy * zs, -1.f), 1.f);
  const float pz = fminf(fmaxf(oz + dz * zs, -1.f), 1.f);

  // ---- per-plane bilinear setup ----
  float w00a, w01a, w10a, w11a, w00b, w01b, w10b, w11b, w00c, w01c, w10c, w11c;
  int off0, off1, off2;
  {
    float fx = (px + 1.f) * 0.5f * 127.f, fy = (py + 1.f) * 0.5f * 127.f;
    int xi = min((int)fx, RES_ - 2), yi = min((int)fy, RES_ - 2);
    float wx = fx - (float)xi, wy = fy - (float)yi;
    w00a = (1.f - wx) * (1.f - wy); w01a = wx * (1.f - wy);
    w10a = (1.f - wx) * wy;         w11a = wx * wy;
    off0 = ((s * 3 + 0) * (RES_ * RES_) + yi * RES_ + xi) * C_;
  }
  {
    float fx = (px + 1.f) * 0.5f * 127.f, fy = (pz + 1.f) * 0.5f * 127.f;
    int xi = min((int)fx, RES_ - 2), yi = min((int)fy, RES_ - 2);
    float wx = fx - (float)xi, wy = fy - (float)yi;
    w00b = (1.f - wx) * (1.f - wy); w01b = wx * (1.f - wy);
    w10b = (1.f - wx) * wy;         w11b = wx * wy;
    off1 = ((s * 3 + 1) * (RES_ * RES_) + yi * RES_ + xi) * C_;
  }
  {
    float fx = (py + 1.f) * 0.5f * 127.f, fy = (pz + 1.f) * 0.5f * 127.f;
    int xi = min((int)fx, RES_ - 2), yi = min((int)fy, RES_ - 2);
    float wx = fx - (float)xi, wy = fy - (float)yi;
    w00c = (1.f - wx) * (1.f - wy); w01c = wx * (1.f - wy);
    w10c = (1.f - wx) * wy;         w11c = wx * wy;
    off2 = ((s * 3 + 2) * (RES_ * RES_) + yi * RES_ + xi) * C_;
  }

  // ---- gather: channels [24q,24q+24) as 3 chunks of 8; f32x2 packed math,
  //      bf16 repack via v_perm truncation (RTZ) ----
#pragma unroll
  for (int u = 0; u < 3; ++u) {
    const int f = 24 * q + 8 * u;  // chunk never crosses a plane boundary
    const int pl = f >> 5;
    const int c = f & 31;
    const int off = (pl == 0) ? off0 : ((pl == 1) ? off1 : off2);
    const float W00 = (pl == 0) ? w00a : ((pl == 1) ? w00b : w00c);
    const float W01 = (pl == 0) ? w01a : ((pl == 1) ? w01b : w01c);
    const float W10 = (pl == 0) ? w10a : ((pl == 1) ? w10b : w10c);
    const float W11 = (pl == 0) ? w11a : ((pl == 1) ? w11b : w11c);
    const unsigned short* bp = codeT + off + c;
    const uint4 A = *(const uint4*)(bp);
    const uint4 B = *(const uint4*)(bp + C_);
    const uint4 Cv = *(const uint4*)(bp + RES_ * C_);
    const uint4 D = *(const uint4*)(bp + RES_ * C_ + C_);
    const unsigned int aw[4] = {A.x, A.y, A.z, A.w};
    const unsigned int bw[4] = {B.x, B.y, B.z, B.w};
    const unsigned int cw[4] = {Cv.x, Cv.y, Cv.z, Cv.w};
    const unsigned int dw[4] = {D.x, D.y, D.z, D.w};
    const f32x2 W00v = {W00, W00}, W01v = {W01, W01}, W10v = {W10, W10}, W11v = {W11, W11};
    unsigned int ow[4];
#pragma unroll
    for (int e2 = 0; e2 < 4; ++e2) {
      const f32x2 va = {__uint_as_float(aw[e2] << 16), __uint_as_float(aw[e2] & 0xffff0000u)};
      const f32x2 vb = {__uint_as_float(bw[e2] << 16), __uint_as_float(bw[e2] & 0xffff0000u)};
      const f32x2 vc = {__uint_as_float(cw[e2] << 16), __uint_as_float(cw[e2] & 0xffff0000u)};
      const f32x2 vd = {__uint_as_float(dw[e2] << 16), __uint_as_float(dw[e2] & 0xffff0000u)};
      const f32x2 fv = W00v * va + W01v * vb + W10v * vc + W11v * vd;
      // out.lo16 = fv[0].hi16 (src1 bytes 2,3); out.hi16 = fv[1].hi16 (src0 bytes 2,3)
      ow[e2] = __builtin_amdgcn_perm(__float_as_uint(fv[1]), __float_as_uint(fv[0]),
                                     0x07060302u);
    }
    *(uint4*)(fA + p * ROWP + f) = make_uint4(ow[0], ow[1], ow[2], ow[3]);
  }
  // wave-local LDS (wave w: rows [16w,16w+16)) -> no barrier.

  // ---- layer 1: feats(64x96) @ W1^T -> h1 bf16 ----
  // afr[0..2] loaded BEFORE any h1 write: fA region then dead -> safe alias.
  f32x4 acc[8];
#pragma unroll
  for (int nt = 0; nt < 8; ++nt) acc[nt] = (f32x4){0.f, 0.f, 0.f, 0.f};
  {
    bf16x8 afr[3];
#pragma unroll
    for (int kt = 0; kt < 3; ++kt)
      afr[kt] = *(const bf16x8*)(fA + (16 * w + ln) * ROWP + kt * 32 + quad * 8);
#pragma unroll
    for (int nt = 0; nt < 8; ++nt) {
      const bf16x8 b0 = *(const bf16x8*)(W1F + ((nt * 3 + 0) * 64 + lane) * 8);
      const bf16x8 b1v = *(const bf16x8*)(W1F + ((nt * 3 + 1) * 64 + lane) * 8);
      const bf16x8 b2v = *(const bf16x8*)(W1F + ((nt * 3 + 2) * 64 + lane) * 8);
      acc[nt] = __builtin_amdgcn_mfma_f32_16x16x32_bf16(afr[0], b0, acc[nt], 0, 0, 0);
      acc[nt] = __builtin_amdgcn_mfma_f32_16x16x32_bf16(afr[1], b1v, acc[nt], 0, 0, 0);
      acc[nt] = __builtin_amdgcn_mfma_f32_16x16x32_bf16(afr[2], b2v, acc[nt], 0, 0, 0);
    }
#pragma unroll
    for (int nt = 0; nt < 8; ++nt) {
      const int n = nt * 16 + ln;
      const float bias = b1[n];
#pragma unroll
      for (int rr = 0; rr < 4; ++rr) {
        const int m = 16 * w + quad * 4 + rr;
        const float v = fmaxf(acc[nt][rr] + bias, 0.f);
        // truncating bf16 store: high half only (ds_write_b16_d16_hi)
        h1s[m * ROWP + n] = (unsigned short)(__float_as_uint(v) >> 16);
      }
    }
  }

  // ---- layer 2: h1(64x128) @ W2^T -> kept in accumulators ----
#pragma unroll
  for (int nt = 0; nt < 8; ++nt) acc[nt] = (f32x4){0.f, 0.f, 0.f, 0.f};
  {
    bf16x8 afr[4];
#pragma unroll
    for (int kt = 0; kt < 4; ++kt)
      afr[kt] = *(const bf16x8*)(h1s + (16 * w + ln) * ROWP + kt * 32 + quad * 8);
#pragma unroll
    for (int nt = 0; nt < 8; ++nt) {
      const bf16x8 b0 = *(const bf16x8*)(W2F + ((nt * 4 + 0) * 64 + lane) * 8);
      const bf16x8 b1v = *(const bf16x8*)(W2F + ((nt * 4 + 1) * 64 + lane) * 8);
      const bf16x8 b2v = *(const bf16x8*)(W2F + ((nt * 4 + 2) * 64 + lane) * 8);
      const bf16x8 b3v = *(const bf16x8*)(W2F + ((nt * 4 + 3) * 64 + lane) * 8);
      acc[nt] = __builtin_amdgcn_mfma_f32_16x16x32_bf16(afr[0], b0, acc[nt], 0, 0, 0);
      acc[nt] = __builtin_amdgcn_mfma_f32_16x16x32_bf16(afr[1], b1v, acc[nt], 0, 0, 0);
      acc[nt] = __builtin_amdgcn_mfma_f32_16x16x32_bf16(afr[2], b2v, acc[nt], 0, 0, 0);
      acc[nt] = __builtin_amdgcn_mfma_f32_16x16x32_bf16(afr[3], b3v, acc[nt], 0, 0, 0);
    }
  }

  // ---- layer 3 in-register: part[rr][q] = sum_n relu(h2)*W3[n][q] ----
  float part[4][4];
#pragma unroll
  for (int rr = 0; rr < 4; ++rr)
#pragma unroll
    for (int qq = 0; qq < 4; ++qq) part[rr][qq] = 0.f;
#pragma unroll
  for (int nt = 0; nt < 8; ++nt) {
    const int n = nt * 16 + ln;
    const float b2n = b2[n];
    const float4 w3v = *(const float4*)(W3 + n * 4);
#pragma unroll
    for (int rr = 0; rr < 4; ++rr) {
      const float hv = fmaxf(acc[nt][rr] + b2n, 0.f);
      part[rr][0] = fmaf(hv, w3v.x, part[rr][0]);
      part[rr][1] = fmaf(hv, w3v.y, part[rr][1]);
      part[rr][2] = fmaf(hv, w3v.z, part[rr][2]);
      part[rr][3] = fmaf(hv, w3v.w, part[rr][3]);
    }
  }
  // pair-halving butterfly over 16 ln-lanes (masks 1/2/4/8 = intra-row DPP)
  float v16[16];
#pragma unroll
  for (int rr = 0; rr < 4; ++rr)
#pragma unroll
    for (int qq = 0; qq < 4; ++qq) v16[rr * 4 + qq] = part[rr][qq];
  float v8[8];
#pragma unroll
  for (int j = 0; j < 8; ++j) {
    const float a = v16[2 * j], c = v16[2 * j + 1];
    const float send = (ln & 1) ? a : c;
    const float keep = (ln & 1) ? c : a;
    v8[j] = keep + __shfl_xor(send, 1);
  }
  float v4a[4];
#pragma unroll
  for (int j = 0; j < 4; ++j) {
    const float a = v8[2 * j], c = v8[2 * j + 1];
    const float send = (ln & 2) ? a : c;
    const float keep = (ln & 2) ? c : a;
    v4a[j] = keep + __shfl_xor(send, 2);
  }
  float v2a[2];
#pragma unroll
  for (int j = 0; j < 2; ++j) {
    const float a = v2a[0] * 0.f + v4a[2 * j], c = v4a[2 * j + 1];
    const float send = (ln & 4) ? a : c;
    const float keep = (ln & 4) ? c : a;
    v2a[j] = keep + __shfl_xor(send, 4);
  }
  float v1;
  {
    const float a = v2a[0], c = v2a[1];
    const float send = (ln & 8) ? a : c;
    const float keep = (ln & 8) ? c : a;
    v1 = keep + __shfl_xor(send, 8);
  }

  // lane -> (m = m_o, q = q_s)
  const float val = v1 + b3[q_s];

  float outv;
  if (q_s == 0) {
    const int occ = (occword >> occbit) & 1;
    const float sp = val > 20.f ? val : log1pf(expf(val));
    outv = occ ? sp : 0.f;
  } else {
    outv = 1.f / (1.f + expf(-val));
  }
  sr[(pG0 + m_o) * 4 + q_s] = outv;
}

// ---------------------------------------------------------------------------
// K2: volume rendering, one wave per ray
// ---------------------------------------------------------------------------
__global__ __launch_bounds__(256) void k_render(
    const float* __restrict__ rays_o, const float* __restrict__ rays_d,
    const float4* __restrict__ sr4, float* __restrict__ out) {
  const int lane = threadIdx.x & 63;
  const int ray = blockIdx.x * 4 + (threadIdx.x >> 6);
  const int s = ray >> 11, r = ray & (R_ - 1);
  const float* ob = rays_o + (s * R_ + r) * 3;
  const float* db = rays_d + (s * R_ + r) * 3;
  float nearv, farv;
  near_far(ob[0], ob[1], ob[2], db[0], db[1], db[2], nearv, farv);
  const float delta = (farv - nearv) * (1.0f / K_);

  const int k0 = lane * 2;
  const float4 A = sr4[ray * K_ + k0];
  const float4 B = sr4[ray * K_ + k0 + 1];
  const float tau0 = A.x * delta, tau1 = B.x * delta;
  const float local = tau0 + tau1;
  float scan = local;
#pragma unroll
  for (int off = 1; off < 64; off <<= 1) {
    const float vsh = __shfl_up(scan, off);
    if (lane >= off) scan += vsh;
  }
  const float pre = scan - local;
  const float T0 = expf(-pre);
  const float T1 = expf(-(pre + tau0));
  const float a0 = 1.f - expf(-tau0);
  const float a1 = 1.f - expf(-tau1);
  const float w0 = (T0 > 1e-4f) ? a0 * T0 : 0.f;
  const float w1 = (T1 > 1e-4f) ? a1 * T1 : 0.f;
  const float z0 = nearv + (farv - nearv) * ((k0 + 0.5f) * (1.f / K_));
  const float z1 = nearv + (farv - nearv) * ((k0 + 1.5f) * (1.f / K_));

  float sw = w0 + w1;
  float sd = w0 * z0 + w1 * z1;
  float sred = w0 * A.y + w1 * B.y;
  float sgrn = w0 * A.z + w1 * B.z;
  float sblu = w0 * A.w + w1 * B.w;
#pragma unroll
  for (int mk = 32; mk >= 1; mk >>= 1) {
    sw += __shfl_xor(sw, mk);
    sd += __shfl_xor(sd, mk);
    sred += __shfl_xor(sred, mk);
    sgrn += __shfl_xor(sgrn, mk);
    sblu += __shfl_xor(sblu, mk);
  }
  if (lane == 0) {
    out[ray] = sw;
    out[S_ * R_ + ray] = sd;
    out[2 * S_ * R_ + ray * 3 + 0] = sred;
    out[2 * S_ * R_ + ray * 3 + 1] = sgrn;
    out[2 * S_ * R_ + ray * 3 + 2] = sblu;
  }
}

// ---------------------------------------------------------------------------
extern "C" void kernel_launch(void* const* d_in, const int* in_sizes, int n_in,
                              void* d_out, int out_size, void* d_ws, size_t ws_size,
                              hipStream_t stream) {
  const float* rays_o = (const float*)d_in[0];
  const float* rays_d = (const float*)d_in[1];
  const float* code = (const float*)d_in[2];
  const int* dgrid = (const int*)d_in[3];
  const float* W1 = (const float*)d_in[5];
  const float* b1 = (const float*)d_in[6];
  const float* W2 = (const float*)d_in[7];
  const float* b2 = (const float*)d_in[8];
  const float* W3 = (const float*)d_in[9];
  const float* b3 = (const float*)d_in[10];

  float* ws = (float*)d_ws;
  unsigned short* codeT = (unsigned short*)(ws + CODET_OFF);
  unsigned short* W1F = (unsigned short*)(ws + W1F_OFF);
  unsigned short* W2F = (unsigned short*)(ws + W2F_OFF);
  unsigned int* gbits = (unsigned int*)(ws + GB_OFF);
  float* sr = ws + SR_OFF;

  hipLaunchKernelGGL(k_pre, dim3(4112), dim3(256), 0, stream,
                     code, codeT, dgrid, gbits, W1, W2, W1F, W2F);
  hipLaunchKernelGGL(k_fused, dim3((S_ * R_ * K_) / 64), dim3(256), 0, stream,
                     rays_o, rays_d, codeT, gbits, W1F, b1, W2F, b2, W3, b3, sr);
  hipLaunchKernelGGL(k_render, dim3((S_ * R_) / 4), dim3(256), 0, stream,
                     rays_o, rays_d, (const float4*)sr, (float*)d_out);
}

// Round 11
// 304.892 us; speedup vs baseline: 1.0809x; 1.0809x over previous
//
#include <hip/hip_runtime.h>
#include <math.h>

#define S_ 4
#define R_ 2048
#define K_ 128
#define C_ 32
#define RES_ 128
#define G_ 128
#define H_ 128

typedef __bf16 bf16x8 __attribute__((ext_vector_type(8)));
typedef float f32x4 __attribute__((ext_vector_type(4)));
typedef float f32x2 __attribute__((ext_vector_type(2)));
typedef unsigned short u16x8 __attribute__((ext_vector_type(8)));

// ws layout (in floats)
#define CODET_OFF 0
#define CODET_SZ  (S_*3*RES_*RES_*C_/2)   // bf16: 3145728 floats
#define W1F_OFF   (CODET_OFF + CODET_SZ)
#define W1F_SZ    (128*96/2)              // 6144 floats
#define W2F_OFF   (W1F_OFF + W1F_SZ)
#define W2F_SZ    (128*128/2)             // 8192 floats
#define GB_OFF    (W2F_OFF + W2F_SZ)
#define GB_SZ     (S_*G_*G_*G_/32)        // 262144 uint words
#define SR_OFF    (GB_OFF + GB_SZ)        // 4194304 floats

// Unified LDS row stride (bf16 elements). 272 B row stride: 16B-multiple
// (aligned b128), consecutive rows offset by 4 banks -> worst 2-way = free.
#define ROWP 136

__device__ __forceinline__ unsigned short f2bf(float x) {
  unsigned int u = __float_as_uint(x);
  unsigned int r = u + 0x7fffu + ((u >> 16) & 1u);
  return (unsigned short)(r >> 16);
}

// ---------------------------------------------------------------------------
// K0 (merged pre-pass):
//   blocks 0..3071   : transpose+cvt code (S,3,C,RES,RES) f32 -> (S,3,RES,RES,C) bf16
//   blocks 3072..4095: density bitmask
//   blocks 4096..4111: weight fragments in MFMA B-operand lane order (16-way split)
// ---------------------------------------------------------------------------
__global__ __launch_bounds__(256) void k_pre(
    const float* __restrict__ src, unsigned short* __restrict__ dst,
    const int* __restrict__ dgrid, unsigned int* __restrict__ gbits,
    const float* __restrict__ W1, const float* __restrict__ W2,
    unsigned short* __restrict__ W1F, unsigned short* __restrict__ W2F) {
  __shared__ float tile[32 * 65];
  const int t = threadIdx.x;
  const int b = blockIdx.x;
  if (b < 3072) {
    const int slab = b >> 8;
    const int xy0 = (b & 255) << 6;
    const float* sp = src + slab * (C_ * RES_ * RES_);
    unsigned short* dp = dst + slab * (RES_ * RES_ * C_);
    const int i = t & 63, cg = t >> 6;
#pragma unroll
    for (int j = 0; j < 8; ++j) {
      int c = cg * 8 + j;
      tile[c * 65 + i] = sp[c * (RES_ * RES_) + xy0 + i];
    }
    __syncthreads();
    const int i2 = t >> 2, sub = t & 3;
    u16x8 pk;
#pragma unroll
    for (int j = 0; j < 8; ++j) pk[j] = f2bf(tile[(sub * 8 + j) * 65 + i2]);
    *(u16x8*)(dp + (xy0 + i2) * C_ + sub * 8) = pk;
  } else if (b < 4096) {
    const int wi = (b - 3072) * 256 + t;
    const int base = wi * 32;
    unsigned int m = 0;
#pragma unroll 8
    for (int j = 0; j < 32; ++j) m |= (dgrid[base + j] > 0 ? (1u << j) : 0u);
    gbits[wi] = m;
  } else {
    const int slice = b - 4096;  // 0..15
    for (int i = slice * 256 + t; i < 128 * 96; i += 16 * 256) {
      const int j = i & 7, lane = (i >> 3) & 63, fi = i >> 9;
      const int nt = fi / 3, kt = fi - 3 * nt;
      const int k = kt * 32 + (lane >> 4) * 8 + j;
      const int n = nt * 16 + (lane & 15);
      W1F[i] = f2bf(W1[k * H_ + n]);
    }
    for (int i = slice * 256 + t; i < 128 * 128; i += 16 * 256) {
      const int j = i & 7, lane = (i >> 3) & 63, fi = i >> 9;
      const int nt = fi >> 2, kt = fi & 3;
      const int k = kt * 32 + (lane >> 4) * 8 + j;
      const int n = nt * 16 + (lane & 15);
      W2F[i] = f2bf(W2[k * H_ + n]);
    }
  }
}

// ---------------------------------------------------------------------------
__device__ __forceinline__ void near_far(float ox, float oy, float oz,
                                         float dx, float dy, float dz,
                                         float& nearv, float& farv) {
  float ddx = fabsf(dx) < 1e-9f ? 1e-9f : dx;
  float ddy = fabsf(dy) < 1e-9f ? 1e-9f : dy;
  float ddz = fabsf(dz) < 1e-9f ? 1e-9f : dz;
  float ix = 1.f / ddx, iy = 1.f / ddy, iz = 1.f / ddz;
  float t1x = (-1.f - ox) * ix, t2x = (1.f - ox) * ix;
  float t1y = (-1.f - oy) * iy, t2y = (1.f - oy) * iy;
  float t1z = (-1.f - oz) * iz, t2z = (1.f - oz) * iz;
  float mnx = fminf(t1x, t2x), mxx = fmaxf(t1x, t2x);
  float mny = fminf(t1y, t2y), mxy = fmaxf(t1y, t2y);
  float mnz = fminf(t1z, t2z), mxz = fmaxf(t1z, t2z);
  nearv = fmaxf(fmaxf(fmaxf(mnx, mny), mnz), 0.2f);
  farv = fmaxf(fminf(fminf(mxx, mxy), mxz), nearv);
}

// ---------------------------------------------------------------------------
// K1: fused sampling + MLP (r9 skeleton: 4 waves, wave-local LDS, aliased
// feats/h1 buffer, no barriers, launch_bounds(256,5) = VGPR 48, no spill).
// Kept from r10: v_perm RTZ bf16 pack in gather; truncating h1 store;
// early occupancy-grid load. Reverted: the (256,8) bound that forced
// VGPR 32 and spilled (WRITE 16->98 MB, r10 post-mortem).
// ---------------------------------------------------------------------------
__global__ __launch_bounds__(256, 5) void k_fused(
    const float* __restrict__ rays_o, const float* __restrict__ rays_d,
    const unsigned short* __restrict__ codeT, const unsigned int* __restrict__ gbits,
    const unsigned short* __restrict__ W1F, const float* __restrict__ b1,
    const unsigned short* __restrict__ W2F, const float* __restrict__ b2,
    const float* __restrict__ W3, const float* __restrict__ b3,
    float* __restrict__ sr) {
  __shared__ __align__(16) unsigned short smem[64 * ROWP];  // 17408 B (fA & h1 alias)
  unsigned short* fA = smem;   // feats: rows [p][0..96)
  unsigned short* h1s = smem;  // h1:    rows [m][0..128)

  const int t = threadIdx.x;
  const int w = t >> 6, lane = t & 63;
  const int quad = lane >> 4, ln = lane & 15;
  const int p = t >> 2, q = t & 3;  // sampling role: point p, channel-quarter q
  const int pG0 = blockIdx.x * 64;
  const int s = blockIdx.x >> 12;
  const int r = (blockIdx.x >> 1) & (R_ - 1);
  const int kbase = (blockIdx.x & 1) * 64;

  const float* ob = rays_o + (s * R_ + r) * 3;
  const float* db = rays_d + (s * R_ + r) * 3;
  const float ox = ob[0], oy = ob[1], oz = ob[2];
  const float dx = db[0], dy = db[1], dz = db[2];
  float nearv, farv;
  near_far(ox, oy, oz, dx, dy, dz, nearv, farv);

  // ---- EARLY occupancy-grid load for this lane's epilogue point m_o ----
  const int q_s = ln & 3, rr_s = ln >> 2;
  const int m_o = 16 * w + quad * 4 + rr_s;
  unsigned int occword;
  int occbit;
  {
    const float zm = nearv + (farv - nearv) * ((kbase + m_o + 0.5f) * (1.0f / K_));
    const float pxm = fminf(fmaxf(ox + dx * zm, -1.f), 1.f);
    const float pym = fminf(fmaxf(oy + dy * zm, -1.f), 1.f);
    const float pzm = fminf(fmaxf(oz + dz * zm, -1.f), 1.f);
    const int i0 = min((int)((pxm + 1.f) * 64.f), G_ - 1);
    const int i1 = min((int)((pym + 1.f) * 64.f), G_ - 1);
    const int i2 = min((int)((pzm + 1.f) * 64.f), G_ - 1);
    const int bidx = ((s * G_ + i0) * G_ + i1) * G_ + i2;
    occword = gbits[bidx >> 5];  // issued early; consumed at the very end
    occbit = bidx & 31;
  }

  // ---- this thread's sample point ----
  const float zs = nearv + (farv - nearv) * ((kbase + p + 0.5f) * (1.0f / K_));
  const float px = fminf(fmaxf(ox + dx * zs, -1.f), 1.f);
  const float py = fminf(fmaxf(oy + dy * zs, -1.f), 1.f);
  const float pz = fminf(fmaxf(oz + dz * zs, -1.f), 1.f);

  // ---- per-plane bilinear setup ----
  float w00a, w01a, w10a, w11a, w00b, w01b, w10b, w11b, w00c, w01c, w10c, w11c;
  int off0, off1, off2;
  {
    float fx = (px + 1.f) * 0.5f * 127.f, fy = (py + 1.f) * 0.5f * 127.f;
    int xi = min((int)fx, RES_ - 2), yi = min((int)fy, RES_ - 2);
    float wx = fx - (float)xi, wy = fy - (float)yi;
    w00a = (1.f - wx) * (1.f - wy); w01a = wx * (1.f - wy);
    w10a = (1.f - wx) * wy;         w11a = wx * wy;
    off0 = ((s * 3 + 0) * (RES_ * RES_) + yi * RES_ + xi) * C_;
  }
  {
    float fx = (px + 1.f) * 0.5f * 127.f, fy = (pz + 1.f) * 0.5f * 127.f;
    int xi = min((int)fx, RES_ - 2), yi = min((int)fy, RES_ - 2);
    float wx = fx - (float)xi, wy = fy - (float)yi;
    w00b = (1.f - wx) * (1.f - wy); w01b = wx * (1.f - wy);
    w10b = (1.f - wx) * wy;         w11b = wx * wy;
    off1 = ((s * 3 + 1) * (RES_ * RES_) + yi * RES_ + xi) * C_;
  }
  {
    float fx = (py + 1.f) * 0.5f * 127.f, fy = (pz + 1.f) * 0.5f * 127.f;
    int xi = min((int)fx, RES_ - 2), yi = min((int)fy, RES_ - 2);
    float wx = fx - (float)xi, wy = fy - (float)yi;
    w00c = (1.f - wx) * (1.f - wy); w01c = wx * (1.f - wy);
    w10c = (1.f - wx) * wy;         w11c = wx * wy;
    off2 = ((s * 3 + 2) * (RES_ * RES_) + yi * RES_ + xi) * C_;
  }

  // ---- gather: channels [24q,24q+24) as 3 chunks of 8; f32x2 packed math,
  //      bf16 repack via v_perm truncation (RTZ) ----
#pragma unroll
  for (int u = 0; u < 3; ++u) {
    const int f = 24 * q + 8 * u;  // chunk never crosses a plane boundary
    const int pl = f >> 5;
    const int c = f & 31;
    const int off = (pl == 0) ? off0 : ((pl == 1) ? off1 : off2);
    const float W00 = (pl == 0) ? w00a : ((pl == 1) ? w00b : w00c);
    const float W01 = (pl == 0) ? w01a : ((pl == 1) ? w01b : w01c);
    const float W10 = (pl == 0) ? w10a : ((pl == 1) ? w10b : w10c);
    const float W11 = (pl == 0) ? w11a : ((pl == 1) ? w11b : w11c);
    const unsigned short* bp = codeT + off + c;
    const uint4 A = *(const uint4*)(bp);
    const uint4 B = *(const uint4*)(bp + C_);
    const uint4 Cv = *(const uint4*)(bp + RES_ * C_);
    const uint4 D = *(const uint4*)(bp + RES_ * C_ + C_);
    const unsigned int aw[4] = {A.x, A.y, A.z, A.w};
    const unsigned int bw[4] = {B.x, B.y, B.z, B.w};
    const unsigned int cw[4] = {Cv.x, Cv.y, Cv.z, Cv.w};
    const unsigned int dw[4] = {D.x, D.y, D.z, D.w};
    const f32x2 W00v = {W00, W00}, W01v = {W01, W01}, W10v = {W10, W10}, W11v = {W11, W11};
    unsigned int ow[4];
#pragma unroll
    for (int e2 = 0; e2 < 4; ++e2) {
      const f32x2 va = {__uint_as_float(aw[e2] << 16), __uint_as_float(aw[e2] & 0xffff0000u)};
      const f32x2 vb = {__uint_as_float(bw[e2] << 16), __uint_as_float(bw[e2] & 0xffff0000u)};
      const f32x2 vc = {__uint_as_float(cw[e2] << 16), __uint_as_float(cw[e2] & 0xffff0000u)};
      const f32x2 vd = {__uint_as_float(dw[e2] << 16), __uint_as_float(dw[e2] & 0xffff0000u)};
      const f32x2 fv = W00v * va + W01v * vb + W10v * vc + W11v * vd;
      // out.lo16 = fv[0].hi16 (src1 bytes 2,3); out.hi16 = fv[1].hi16 (src0 bytes 2,3)
      ow[e2] = __builtin_amdgcn_perm(__float_as_uint(fv[1]), __float_as_uint(fv[0]),
                                     0x07060302u);
    }
    *(uint4*)(fA + p * ROWP + f) = make_uint4(ow[0], ow[1], ow[2], ow[3]);
  }
  // wave-local LDS (wave w: rows [16w,16w+16)) -> no barrier.

  // ---- layer 1: feats(64x96) @ W1^T -> h1 bf16 ----
  // afr[0..2] loaded BEFORE any h1 write: fA region then dead -> safe alias.
  f32x4 acc[8];
#pragma unroll
  for (int nt = 0; nt < 8; ++nt) acc[nt] = (f32x4){0.f, 0.f, 0.f, 0.f};
  {
    bf16x8 afr[3];
#pragma unroll
    for (int kt = 0; kt < 3; ++kt)
      afr[kt] = *(const bf16x8*)(fA + (16 * w + ln) * ROWP + kt * 32 + quad * 8);
#pragma unroll
    for (int nt = 0; nt < 8; ++nt) {
      const bf16x8 b0 = *(const bf16x8*)(W1F + ((nt * 3 + 0) * 64 + lane) * 8);
      const bf16x8 b1v = *(const bf16x8*)(W1F + ((nt * 3 + 1) * 64 + lane) * 8);
      const bf16x8 b2v = *(const bf16x8*)(W1F + ((nt * 3 + 2) * 64 + lane) * 8);
      acc[nt] = __builtin_amdgcn_mfma_f32_16x16x32_bf16(afr[0], b0, acc[nt], 0, 0, 0);
      acc[nt] = __builtin_amdgcn_mfma_f32_16x16x32_bf16(afr[1], b1v, acc[nt], 0, 0, 0);
      acc[nt] = __builtin_amdgcn_mfma_f32_16x16x32_bf16(afr[2], b2v, acc[nt], 0, 0, 0);
    }
#pragma unroll
    for (int nt = 0; nt < 8; ++nt) {
      const int n = nt * 16 + ln;
      const float bias = b1[n];
#pragma unroll
      for (int rr = 0; rr < 4; ++rr) {
        const int m = 16 * w + quad * 4 + rr;
        const float v = fmaxf(acc[nt][rr] + bias, 0.f);
        // truncating bf16 store: high half only (ds_write_b16_d16_hi)
        h1s[m * ROWP + n] = (unsigned short)(__float_as_uint(v) >> 16);
      }
    }
  }

  // ---- layer 2: h1(64x128) @ W2^T -> kept in accumulators ----
#pragma unroll
  for (int nt = 0; nt < 8; ++nt) acc[nt] = (f32x4){0.f, 0.f, 0.f, 0.f};
  {
    bf16x8 afr[4];
#pragma unroll
    for (int kt = 0; kt < 4; ++kt)
      afr[kt] = *(const bf16x8*)(h1s + (16 * w + ln) * ROWP + kt * 32 + quad * 8);
#pragma unroll
    for (int nt = 0; nt < 8; ++nt) {
      const bf16x8 b0 = *(const bf16x8*)(W2F + ((nt * 4 + 0) * 64 + lane) * 8);
      const bf16x8 b1v = *(const bf16x8*)(W2F + ((nt * 4 + 1) * 64 + lane) * 8);
      const bf16x8 b2v = *(const bf16x8*)(W2F + ((nt * 4 + 2) * 64 + lane) * 8);
      const bf16x8 b3v = *(const bf16x8*)(W2F + ((nt * 4 + 3) * 64 + lane) * 8);
      acc[nt] = __builtin_amdgcn_mfma_f32_16x16x32_bf16(afr[0], b0, acc[nt], 0, 0, 0);
      acc[nt] = __builtin_amdgcn_mfma_f32_16x16x32_bf16(afr[1], b1v, acc[nt], 0, 0, 0);
      acc[nt] = __builtin_amdgcn_mfma_f32_16x16x32_bf16(afr[2], b2v, acc[nt], 0, 0, 0);
      acc[nt] = __builtin_amdgcn_mfma_f32_16x16x32_bf16(afr[3], b3v, acc[nt], 0, 0, 0);
    }
  }

  // ---- layer 3 in-register: part[rr][q] = sum_n relu(h2)*W3[n][q] ----
  float part[4][4];
#pragma unroll
  for (int rr = 0; rr < 4; ++rr)
#pragma unroll
    for (int qq = 0; qq < 4; ++qq) part[rr][qq] = 0.f;
#pragma unroll
  for (int nt = 0; nt < 8; ++nt) {
    const int n = nt * 16 + ln;
    const float b2n = b2[n];
    const float4 w3v = *(const float4*)(W3 + n * 4);
#pragma unroll
    for (int rr = 0; rr < 4; ++rr) {
      const float hv = fmaxf(acc[nt][rr] + b2n, 0.f);
      part[rr][0] = fmaf(hv, w3v.x, part[rr][0]);
      part[rr][1] = fmaf(hv, w3v.y, part[rr][1]);
      part[rr][2] = fmaf(hv, w3v.z, part[rr][2]);
      part[rr][3] = fmaf(hv, w3v.w, part[rr][3]);
    }
  }
  // pair-halving butterfly over 16 ln-lanes (masks 1/2/4/8 = intra-row DPP)
  float v16[16];
#pragma unroll
  for (int rr = 0; rr < 4; ++rr)
#pragma unroll
    for (int qq = 0; qq < 4; ++qq) v16[rr * 4 + qq] = part[rr][qq];
  float v8[8];
#pragma unroll
  for (int j = 0; j < 8; ++j) {
    const float a = v16[2 * j], c = v16[2 * j + 1];
    const float send = (ln & 1) ? a : c;
    const float keep = (ln & 1) ? c : a;
    v8[j] = keep + __shfl_xor(send, 1);
  }
  float v4a[4];
#pragma unroll
  for (int j = 0; j < 4; ++j) {
    const float a = v8[2 * j], c = v8[2 * j + 1];
    const float send = (ln & 2) ? a : c;
    const float keep = (ln & 2) ? c : a;
    v4a[j] = keep + __shfl_xor(send, 2);
  }
  float v2a[2];
#pragma unroll
  for (int j = 0; j < 2; ++j) {
    const float a = v4a[2 * j], c = v4a[2 * j + 1];
    const float send = (ln & 4) ? a : c;
    const float keep = (ln & 4) ? c : a;
    v2a[j] = keep + __shfl_xor(send, 4);
  }
  float v1;
  {
    const float a = v2a[0], c = v2a[1];
    const float send = (ln & 8) ? a : c;
    const float keep = (ln & 8) ? c : a;
    v1 = keep + __shfl_xor(send, 8);
  }

  // lane -> (m = m_o, q = q_s)
  const float val = v1 + b3[q_s];

  float outv;
  if (q_s == 0) {
    const int occ = (occword >> occbit) & 1;
    const float sp = val > 20.f ? val : log1pf(expf(val));
    outv = occ ? sp : 0.f;
  } else {
    outv = 1.f / (1.f + expf(-val));
  }
  sr[(pG0 + m_o) * 4 + q_s] = outv;
}

// ---------------------------------------------------------------------------
// K2: volume rendering, one wave per ray
// ---------------------------------------------------------------------------
__global__ __launch_bounds__(256) void k_render(
    const float* __restrict__ rays_o, const float* __restrict__ rays_d,
    const float4* __restrict__ sr4, float* __restrict__ out) {
  const int lane = threadIdx.x & 63;
  const int ray = blockIdx.x * 4 + (threadIdx.x >> 6);
  const int s = ray >> 11, r = ray & (R_ - 1);
  const float* ob = rays_o + (s * R_ + r) * 3;
  const float* db = rays_d + (s * R_ + r) * 3;
  float nearv, farv;
  near_far(ob[0], ob[1], ob[2], db[0], db[1], db[2], nearv, farv);
  const float delta = (farv - nearv) * (1.0f / K_);

  const int k0 = lane * 2;
  const float4 A = sr4[ray * K_ + k0];
  const float4 B = sr4[ray * K_ + k0 + 1];
  const float tau0 = A.x * delta, tau1 = B.x * delta;
  const float local = tau0 + tau1;
  float scan = local;
#pragma unroll
  for (int off = 1; off < 64; off <<= 1) {
    const float vsh = __shfl_up(scan, off);
    if (lane >= off) scan += vsh;
  }
  const float pre = scan - local;
  const float T0 = expf(-pre);
  const float T1 = expf(-(pre + tau0));
  const float a0 = 1.f - expf(-tau0);
  const float a1 = 1.f - expf(-tau1);
  const float w0 = (T0 > 1e-4f) ? a0 * T0 : 0.f;
  const float w1 = (T1 > 1e-4f) ? a1 * T1 : 0.f;
  const float z0 = nearv + (farv - nearv) * ((k0 + 0.5f) * (1.f / K_));
  const float z1 = nearv + (farv - nearv) * ((k0 + 1.5f) * (1.f / K_));

  float sw = w0 + w1;
  float sd = w0 * z0 + w1 * z1;
  float sred = w0 * A.y + w1 * B.y;
  float sgrn = w0 * A.z + w1 * B.z;
  float sblu = w0 * A.w + w1 * B.w;
#pragma unroll
  for (int mk = 32; mk >= 1; mk >>= 1) {
    sw += __shfl_xor(sw, mk);
    sd += __shfl_xor(sd, mk);
    sred += __shfl_xor(sred, mk);
    sgrn += __shfl_xor(sgrn, mk);
    sblu += __shfl_xor(sblu, mk);
  }
  if (lane == 0) {
    out[ray] = sw;
    out[S_ * R_ + ray] = sd;
    out[2 * S_ * R_ + ray * 3 + 0] = sred;
    out[2 * S_ * R_ + ray * 3 + 1] = sgrn;
    out[2 * S_ * R_ + ray * 3 + 2] = sblu;
  }
}

// ---------------------------------------------------------------------------
extern "C" void kernel_launch(void* const* d_in, const int* in_sizes, int n_in,
                              void* d_out, int out_size, void* d_ws, size_t ws_size,
                              hipStream_t stream) {
  const float* rays_o = (const float*)d_in[0];
  const float* rays_d = (const float*)d_in[1];
  const float* code = (const float*)d_in[2];
  const int* dgrid = (const int*)d_in[3];
  const float* W1 = (const float*)d_in[5];
  const float* b1 = (const float*)d_in[6];
  const float* W2 = (const float*)d_in[7];
  const float* b2 = (const float*)d_in[8];
  const float* W3 = (const float*)d_in[9];
  const float* b3 = (const float*)d_in[10];

  float* ws = (float*)d_ws;
  unsigned short* codeT = (unsigned short*)(ws + CODET_OFF);
  unsigned short* W1F = (unsigned short*)(ws + W1F_OFF);
  unsigned short* W2F = (unsigned short*)(ws + W2F_OFF);
  unsigned int* gbits = (unsigned int*)(ws + GB_OFF);
  float* sr = ws + SR_OFF;

  hipLaunchKernelGGL(k_pre, dim3(4112), dim3(256), 0, stream,
                     code, codeT, dgrid, gbits, W1, W2, W1F, W2F);
  hipLaunchKernelGGL(k_fused, dim3((S_ * R_ * K_) / 64), dim3(256), 0, stream,
                     rays_o, rays_d, codeT, gbits, W1F, b1, W2F, b2, W3, b3, sr);
  hipLaunchKernelGGL(k_render, dim3((S_ * R_) / 4), dim3(256), 0, stream,
                     rays_o, rays_d, (const float4*)sr, (float*)d_out);
}